// Round 9
// baseline (444.348 us; speedup 1.0000x reference)
//
#include <hip/hip_runtime.h>
#include <hip/hip_bf16.h>
#include <math.h>

#define N_LAYERS 3
#define ENT 64
#define NODE_DIM 128
#define PROW 192   // 3 layers * 64 fp16 per node (per side)

typedef _Float16 f16x8 __attribute__((ext_vector_type(8)));
typedef __fp16 fp16x2 __attribute__((ext_vector_type(2)));
typedef float f32x4 __attribute__((ext_vector_type(4)));

__device__ __forceinline__ float tanh_fast(float x) {
    const float e = __builtin_amdgcn_exp2f(fminf(x, 20.0f) * 2.8853900817779268f);
    return __builtin_fmaf(-2.0f, __builtin_amdgcn_rcpf(e + 1.0f), 1.0f);
}

__device__ __forceinline__ f16x8 pack_f16(const float h[8]) {
    union { fp16x2 p[4]; f16x8 v; } u;
    u.p[0] = __builtin_amdgcn_cvt_pkrtz(h[0], h[1]);
    u.p[1] = __builtin_amdgcn_cvt_pkrtz(h[2], h[3]);
    u.p[2] = __builtin_amdgcn_cvt_pkrtz(h[4], h[5]);
    u.p[3] = __builtin_amdgcn_cvt_pkrtz(h[6], h[7]);
    return u.v;
}

// ---------------- build f16 B-fragments of W2 / M / W1 ----------
// W2/M: frag idx = (l*2+{0:W2,1:M})*8 + t*2 + s         (48 frags)
// W1:   frag idx = 48 + (l*2+half)*16 + t*4 + s         (96 frags)
// lane holds B[k = s*32 + (lane>>4)*8 + j][n = t*16 + (lane&15)]
__global__ __launch_bounds__(256) void build_frags(
    const float* __restrict__ W2, const float* __restrict__ Mw,
    const float* __restrict__ W1, _Float16* __restrict__ frags)
{
    const int id = blockIdx.x * 256 + threadIdx.x;
    const int lane = id & 63;
    const int lgrp = lane >> 4, lmod = lane & 15;
    if (id < 48 * 64) {
        const int frag = (id >> 6) & 7;
        const int mat = id >> 9;                  // 0..5 = l*2 + {W2,M}
        const int l = mat >> 1;
        const float* W = (mat & 1) ? Mw : W2;
        const int t = frag >> 1, s = frag & 1;
        const int ncol = t * 16 + lmod;
        const int k0 = s * 32 + lgrp * 8;
        _Float16* dst = frags + ((mat * 8 + frag) * 64 + lane) * 8;
#pragma unroll
        for (int j = 0; j < 8; ++j)
            dst[j] = (_Float16)W[l * 4096 + (k0 + j) * 64 + ncol];
    } else if (id < 144 * 64) {
        const int wid = id - 48 * 64;
        const int f = wid >> 6;                   // 0..95
        const int l = f >> 5;
        const int rem = f & 31;
        const int half = rem >> 4;
        const int t = (rem >> 2) & 3;
        const int s = rem & 3;
        const int ncol = t * 16 + lmod;
        const int krow = half * 128 + s * 32 + lgrp * 8;
        _Float16* dst = frags + ((48 + f) * 64 + lane) * 8;
#pragma unroll
        for (int j = 0; j < 8; ++j)
            dst[j] = (_Float16)W1[(l * 256 + krow + j) * 64 + ncol];
    }
}

// ---------------- per-node projection via f16 MFMA --------------
// Prow[n][l*64+j] = sum_k nf[n][k]W1[l][k][j] + b1[l][j];  Pcol: k=128..255, no bias
__global__ __launch_bounds__(256) void proj_mfma(
    const float* __restrict__ nf, const _Float16* __restrict__ frags,
    const float* __restrict__ b1,
    _Float16* __restrict__ Prow, _Float16* __restrict__ Pcol, int nNodes)
{
    const int tid = threadIdx.x, lane = tid & 63, wv = tid >> 6;
    const int lgrp = lane >> 4, lmod = lane & 15;
    const int n0 = (blockIdx.x * 4 + wv) * 16;
    if (n0 >= nNodes) return;
    int nn = n0 + lmod; if (nn >= nNodes) nn = nNodes - 1;
    const float* nfr = nf + (long)nn * NODE_DIM;

    f16x8 a[4];
#pragma unroll
    for (int s = 0; s < 4; ++s) {
        const float4 q0 = *(const float4*)(nfr + s * 32 + lgrp * 8);
        const float4 q1 = *(const float4*)(nfr + s * 32 + lgrp * 8 + 4);
        const float h[8] = {q0.x, q0.y, q0.z, q0.w, q1.x, q1.y, q1.z, q1.w};
        a[s] = pack_f16(h);
    }
    const f16x8* fb = (const f16x8*)frags;
#pragma unroll
    for (int l = 0; l < N_LAYERS; ++l) {
#pragma unroll
        for (int half = 0; half < 2; ++half) {
            f32x4 c[4];
#pragma unroll
            for (int t = 0; t < 4; ++t) {
                const float bv = (half == 0) ? b1[l * 64 + t * 16 + lmod] : 0.f;
                c[t] = (f32x4){bv, bv, bv, bv};
            }
#pragma unroll
            for (int t = 0; t < 4; ++t)
#pragma unroll
                for (int s = 0; s < 4; ++s)
                    c[t] = __builtin_amdgcn_mfma_f32_16x16x32_f16(
                        a[s], fb[((48 + (l * 2 + half) * 16 + t * 4 + s)) * 64 + lane], c[t], 0, 0, 0);
            _Float16* dst = half ? Pcol : Prow;
#pragma unroll
            for (int t = 0; t < 4; ++t)
#pragma unroll
                for (int r = 0; r < 4; ++r) {
                    const int node = n0 + lgrp * 4 + r;
                    if (node < nNodes)
                        dst[(long)node * PROW + l * 64 + t * 16 + lmod] = (_Float16)c[t][r];
                }
        }
    }
}

// ---------------- fused per-edge pipeline, f16 MFMA -------------
// R8 structure; single change: ALL 3 layers' gathers hoisted to batch start.
__global__ __launch_bounds__(256, 2) void edge_mfma(
    const _Float16* __restrict__ Prow, const _Float16* __restrict__ Pcol,
    const int* __restrict__ ei,
    const float* __restrict__ b2, const float* __restrict__ gamma,
    const float* __restrict__ beta, const _Float16* __restrict__ frags,
    float* __restrict__ out, int E)
{
    __shared__ __align__(16) float tr[4][16 * 68];   // per-wave scratch, pad 68
    const int tid = threadIdx.x, lane = tid & 63, wv = tid >> 6;
    float* mytr = tr[wv];
    const int lgrp = lane >> 4, lmod = lane & 15;

    // bell bpermute lane sources (byte addresses)
    const int gbase = lane & 48;
    const int sA = (lmod < 4) ? (gbase + (lmod >> 1)) : lane;
    const int sB = (lmod < 4) ? (gbase + 3 - (lmod >> 1)) : lane;
    const int idxA = sA << 2, idxB = sB << 2;
    const float signB = (lmod & 1) ? -0.70710678118f : 0.70710678118f;

    const f16x8* fb = (const f16x8*)frags;

    const int nb = (E + 31) >> 5;               // batches of 32 edges
    const int gw = (blockIdx.x << 2) + wv;
    const int nw = gridDim.x << 2;

    for (int b = gw; b < nb; b += nw) {
        const int e0 = b << 5;
        int rn[2], cn[2];
#pragma unroll
        for (int mt = 0; mt < 2; ++mt) {
            int e = e0 + mt * 16 + lmod;
            int ec = (e < E) ? e : (E - 1);
            rn[mt] = ei[ec];
            cn[mt] = ei[E + ec];
        }

        // --- issue ALL gathers for ALL 3 layers upfront (24 x 16B per lane)
        f16x8 g1[2][N_LAYERS][2], g2[2][N_LAYERS][2];
#pragma unroll
        for (int mt = 0; mt < 2; ++mt) {
            const _Float16* p1 = Prow + (long)rn[mt] * PROW;
            const _Float16* p2 = Pcol + (long)cn[mt] * PROW;
#pragma unroll
            for (int l = 0; l < N_LAYERS; ++l)
#pragma unroll
                for (int s = 0; s < 2; ++s) {
                    g1[mt][l][s] = *(const f16x8*)(p1 + l * 64 + s * 32 + lgrp * 8);
                    g2[mt][l][s] = *(const f16x8*)(p2 + l * 64 + s * 32 + lgrp * 8);
                }
        }

        f32x4 tot[2][4];
#pragma unroll
        for (int mt = 0; mt < 2; ++mt)
#pragma unroll
            for (int t = 0; t < 4; ++t) tot[mt][t] = (f32x4){0.f, 0.f, 0.f, 0.f};

#pragma unroll
        for (int l = 0; l < N_LAYERS; ++l) {
            // weight B-frags (L1/L2-hot)
            f16x8 w2f[4][2], mf[4][2];
#pragma unroll
            for (int t = 0; t < 4; ++t)
#pragma unroll
                for (int s = 0; s < 2; ++s) {
                    w2f[t][s] = fb[((l * 2) * 8 + t * 2 + s) * 64 + lane];
                    mf[t][s]  = fb[((l * 2 + 1) * 8 + t * 2 + s) * 64 + lane];
                }
            float b2v[4], gv[4], bev[4];
#pragma unroll
            for (int t = 0; t < 4; ++t) {
                b2v[t] = b2[l * 64 + t * 16 + lmod];
                gv[t]  = gamma[l * 64 + t * 16 + lmod];
                bev[t] = beta[l * 64 + t * 16 + lmod];
            }

#pragma unroll
            for (int mt = 0; mt < 2; ++mt) {
                // --- A-frag of H = tanh(prow + pcol) (b1 pre-folded)
                f16x8 a[2];
#pragma unroll
                for (int s = 0; s < 2; ++s) {
                    const f16x8 z = g1[mt][l][s] + g2[mt][l][s];   // v_pk_add_f16
                    float h[8];
#pragma unroll
                    for (int j = 0; j < 8; ++j) h[j] = tanh_fast((float)z[j]);
                    a[s] = pack_f16(h);
                }

                // --- C1 = H @ W2 + b2
                f32x4 c1[4];
#pragma unroll
                for (int t = 0; t < 4; ++t)
                    c1[t] = (f32x4){b2v[t], b2v[t], b2v[t], b2v[t]};
#pragma unroll
                for (int t = 0; t < 4; ++t)
#pragma unroll
                    for (int s = 0; s < 2; ++s)
                        c1[t] = __builtin_amdgcn_mfma_f32_16x16x32_f16(a[s], w2f[t][s], c1[t], 0, 0, 0);

                // --- LayerNorm rows + write normalized to LDS (pad-68)
#pragma unroll
                for (int r = 0; r < 4; ++r) {
                    float s1 = (c1[0][r] + c1[1][r]) + (c1[2][r] + c1[3][r]);
                    float s2 = __builtin_fmaf(c1[0][r], c1[0][r],
                               __builtin_fmaf(c1[1][r], c1[1][r],
                               __builtin_fmaf(c1[2][r], c1[2][r], c1[3][r] * c1[3][r])));
#pragma unroll
                    for (int off = 1; off < 16; off <<= 1) {
                        s1 += __shfl_xor(s1, off, 64);
                        s2 += __shfl_xor(s2, off, 64);
                    }
                    const float mu = s1 * 0.015625f;
                    const float var = __builtin_fmaf(s2, 0.015625f, -mu * mu);
                    const float rs = __builtin_amdgcn_rsqf(var + 1e-5f);
                    const int rowbase = (lgrp * 4 + r) * 68;
#pragma unroll
                    for (int t = 0; t < 4; ++t) {
                        const float At = rs * gv[t];
                        const float Bt = __builtin_fmaf(-mu, At, bev[t]);
                        mytr[rowbase + lmod + 16 * t] = __builtin_fmaf(c1[t][r], At, Bt);
                    }
                }
                __builtin_amdgcn_wave_barrier();

                // --- transpose-read as A-frag (row=lmod, k=s*32+lgrp*8+j)
                f16x8 a2[2];
#pragma unroll
                for (int s = 0; s < 2; ++s) {
                    const float* rp = mytr + lmod * 68 + s * 32 + lgrp * 8;
                    const float4 q0 = *(const float4*)rp;
                    const float4 q1 = *(const float4*)(rp + 4);
                    const float h[8] = {q0.x, q0.y, q0.z, q0.w, q1.x, q1.y, q1.z, q1.w};
                    a2[s] = pack_f16(h);
                }
                __builtin_amdgcn_wave_barrier();

                // --- C2 = Hn @ M
                f32x4 c2[4];
#pragma unroll
                for (int t = 0; t < 4; ++t) c2[t] = (f32x4){0.f, 0.f, 0.f, 0.f};
#pragma unroll
                for (int t = 0; t < 4; ++t)
#pragma unroll
                    for (int s = 0; s < 2; ++s)
                        c2[t] = __builtin_amdgcn_mfma_f32_16x16x32_f16(a2[s], mf[t][s], c2[t], 0, 0, 0);

                // --- Bell projection on channels 0..3 via ds_bpermute
#pragma unroll
                for (int r = 0; r < 4; ++r) {
                    const float m0 = c2[0][r];
                    const float vA = __int_as_float(__builtin_amdgcn_ds_bpermute(idxA, __float_as_int(m0)));
                    const float vB = __int_as_float(__builtin_amdgcn_ds_bpermute(idxB, __float_as_int(m0)));
                    const float mixed = __builtin_fmaf(vB, signB, vA * 0.70710678118f);
                    tot[mt][0][r] += (lmod < 4) ? mixed : m0;
                }
#pragma unroll
                for (int t = 1; t < 4; ++t) tot[mt][t] += c2[t];
            } // mt
        } // l

        // --- L2 normalize, stage in LDS, coalesced f32x4 stores
#pragma unroll
        for (int mt = 0; mt < 2; ++mt) {
#pragma unroll
            for (int r = 0; r < 4; ++r) {
                float q = __builtin_fmaf(tot[mt][0][r], tot[mt][0][r],
                          __builtin_fmaf(tot[mt][1][r], tot[mt][1][r],
                          __builtin_fmaf(tot[mt][2][r], tot[mt][2][r],
                                         tot[mt][3][r] * tot[mt][3][r])));
#pragma unroll
                for (int off = 1; off < 16; off <<= 1) q += __shfl_xor(q, off, 64);
                const float inv = 1.0f / (sqrtf(q) + 1e-8f);
                const int rowloc = lgrp * 4 + r;
#pragma unroll
                for (int t = 0; t < 4; ++t)
                    mytr[rowloc * 64 + lmod + 16 * t] = tot[mt][t][r] * inv;
            }
            __builtin_amdgcn_wave_barrier();
#pragma unroll
            for (int i = 0; i < 4; ++i) {
                const int row = i * 4 + lgrp;
                const int c4 = lmod * 4;
                const int e = e0 + mt * 16 + row;
                if (e < E) {
                    const f32x4 v = *(const f32x4*)&mytr[row * 64 + c4];
                    *(f32x4*)(out + (long)e * 64 + c4) = v;
                }
            }
            __builtin_amdgcn_wave_barrier();
        }
    }
}

extern "C" void kernel_launch(void* const* d_in, const int* in_sizes, int n_in,
                              void* d_out, int out_size, void* d_ws, size_t ws_size,
                              hipStream_t stream) {
    const float* nf    = (const float*)d_in[0];
    const int*   ei    = (const int*)d_in[1];
    const float* W1    = (const float*)d_in[2];
    const float* b1    = (const float*)d_in[3];
    const float* W2    = (const float*)d_in[4];
    const float* b2    = (const float*)d_in[5];
    const float* gamma = (const float*)d_in[6];
    const float* beta  = (const float*)d_in[7];
    const float* Mw    = (const float*)d_in[8];
    float* out = (float*)d_out;

    const int nNodes = in_sizes[0] / NODE_DIM;
    const int E = in_sizes[1] / 2;

    _Float16* Prow = (_Float16*)d_ws;
    _Float16* Pcol = Prow + (size_t)nNodes * PROW;
    _Float16* frags = Pcol + (size_t)nNodes * PROW;   // 144 frags * 1KB

    build_frags<<<36, 256, 0, stream>>>(W2, Mw, W1, frags);
    proj_mfma<<<(nNodes / 16 + 3) / 4 + 1, 256, 0, stream>>>(nf, frags, b1, Prow, Pcol, nNodes);

    edge_mfma<<<2048, 256, 0, stream>>>(Prow, Pcol, ei, b2, gamma, beta, frags, out, E);
}

// Round 10
// 420.664 us; speedup vs baseline: 1.0563x; 1.0563x over previous
//
#include <hip/hip_runtime.h>
#include <hip/hip_bf16.h>
#include <math.h>

#define N_LAYERS 3
#define ENT 64
#define NODE_DIM 128
#define PROW 192   // 3 layers * 64 fp16 per node (per side)

typedef _Float16 f16x8 __attribute__((ext_vector_type(8)));
typedef __fp16 fp16x2 __attribute__((ext_vector_type(2)));
typedef float f32x4 __attribute__((ext_vector_type(4)));

__device__ __forceinline__ float tanh_fast(float x) {
    const float e = __builtin_amdgcn_exp2f(fminf(x, 20.0f) * 2.8853900817779268f);
    return __builtin_fmaf(-2.0f, __builtin_amdgcn_rcpf(e + 1.0f), 1.0f);
}

__device__ __forceinline__ f16x8 pack_f16(const float h[8]) {
    union { fp16x2 p[4]; f16x8 v; } u;
    u.p[0] = __builtin_amdgcn_cvt_pkrtz(h[0], h[1]);
    u.p[1] = __builtin_amdgcn_cvt_pkrtz(h[2], h[3]);
    u.p[2] = __builtin_amdgcn_cvt_pkrtz(h[4], h[5]);
    u.p[3] = __builtin_amdgcn_cvt_pkrtz(h[6], h[7]);
    return u.v;
}

// ---------------- build f16 B-fragments of W2 / M / W1 ----------
// W2/M: frag idx = (l*2+{0:W2,1:M})*8 + t*2 + s         (48 frags)
// W1:   frag idx = 48 + (l*2+half)*16 + t*4 + s         (96 frags)
// lane holds B[k = s*32 + (lane>>4)*8 + j][n = t*16 + (lane&15)]
__global__ __launch_bounds__(256) void build_frags(
    const float* __restrict__ W2, const float* __restrict__ Mw,
    const float* __restrict__ W1, _Float16* __restrict__ frags)
{
    const int id = blockIdx.x * 256 + threadIdx.x;
    const int lane = id & 63;
    const int lgrp = lane >> 4, lmod = lane & 15;
    if (id < 48 * 64) {
        const int frag = (id >> 6) & 7;
        const int mat = id >> 9;                  // 0..5 = l*2 + {W2,M}
        const int l = mat >> 1;
        const float* W = (mat & 1) ? Mw : W2;
        const int t = frag >> 1, s = frag & 1;
        const int ncol = t * 16 + lmod;
        const int k0 = s * 32 + lgrp * 8;
        _Float16* dst = frags + ((mat * 8 + frag) * 64 + lane) * 8;
#pragma unroll
        for (int j = 0; j < 8; ++j)
            dst[j] = (_Float16)W[l * 4096 + (k0 + j) * 64 + ncol];
    } else if (id < 144 * 64) {
        const int wid = id - 48 * 64;
        const int f = wid >> 6;                   // 0..95
        const int l = f >> 5;
        const int rem = f & 31;
        const int half = rem >> 4;
        const int t = (rem >> 2) & 3;
        const int s = rem & 3;
        const int ncol = t * 16 + lmod;
        const int krow = half * 128 + s * 32 + lgrp * 8;
        _Float16* dst = frags + ((48 + f) * 64 + lane) * 8;
#pragma unroll
        for (int j = 0; j < 8; ++j)
            dst[j] = (_Float16)W1[(l * 256 + krow + j) * 64 + ncol];
    }
}

// ---------------- per-node projection via f16 MFMA --------------
// Prow[n][l*64+j] = sum_k nf[n][k]W1[l][k][j] + b1[l][j];  Pcol: k=128..255, no bias
__global__ __launch_bounds__(256) void proj_mfma(
    const float* __restrict__ nf, const _Float16* __restrict__ frags,
    const float* __restrict__ b1,
    _Float16* __restrict__ Prow, _Float16* __restrict__ Pcol, int nNodes)
{
    const int tid = threadIdx.x, lane = tid & 63, wv = tid >> 6;
    const int lgrp = lane >> 4, lmod = lane & 15;
    const int n0 = (blockIdx.x * 4 + wv) * 16;
    if (n0 >= nNodes) return;
    int nn = n0 + lmod; if (nn >= nNodes) nn = nNodes - 1;
    const float* nfr = nf + (long)nn * NODE_DIM;

    f16x8 a[4];
#pragma unroll
    for (int s = 0; s < 4; ++s) {
        const float4 q0 = *(const float4*)(nfr + s * 32 + lgrp * 8);
        const float4 q1 = *(const float4*)(nfr + s * 32 + lgrp * 8 + 4);
        const float h[8] = {q0.x, q0.y, q0.z, q0.w, q1.x, q1.y, q1.z, q1.w};
        a[s] = pack_f16(h);
    }
    const f16x8* fb = (const f16x8*)frags;
#pragma unroll
    for (int l = 0; l < N_LAYERS; ++l) {
#pragma unroll
        for (int half = 0; half < 2; ++half) {
            f32x4 c[4];
#pragma unroll
            for (int t = 0; t < 4; ++t) {
                const float bv = (half == 0) ? b1[l * 64 + t * 16 + lmod] : 0.f;
                c[t] = (f32x4){bv, bv, bv, bv};
            }
#pragma unroll
            for (int t = 0; t < 4; ++t)
#pragma unroll
                for (int s = 0; s < 4; ++s)
                    c[t] = __builtin_amdgcn_mfma_f32_16x16x32_f16(
                        a[s], fb[((48 + (l * 2 + half) * 16 + t * 4 + s)) * 64 + lane], c[t], 0, 0, 0);
            _Float16* dst = half ? Pcol : Prow;
#pragma unroll
            for (int t = 0; t < 4; ++t)
#pragma unroll
                for (int r = 0; r < 4; ++r) {
                    const int node = n0 + lgrp * 4 + r;
                    if (node < nNodes)
                        dst[(long)node * PROW + l * 64 + t * 16 + lmod] = (_Float16)c[t][r];
                }
        }
    }
}

// ---------------- fused per-edge pipeline, f16 MFMA (R8 = best) -----------
__global__ __launch_bounds__(256, 2) void edge_mfma(
    const _Float16* __restrict__ Prow, const _Float16* __restrict__ Pcol,
    const int* __restrict__ ei,
    const float* __restrict__ b2, const float* __restrict__ gamma,
    const float* __restrict__ beta, const _Float16* __restrict__ frags,
    float* __restrict__ out, int E)
{
    __shared__ __align__(16) float tr[4][16 * 68];   // per-wave scratch, pad 68
    const int tid = threadIdx.x, lane = tid & 63, wv = tid >> 6;
    float* mytr = tr[wv];
    const int lgrp = lane >> 4, lmod = lane & 15;

    // bell bpermute lane sources (byte addresses)
    const int gbase = lane & 48;
    const int sA = (lmod < 4) ? (gbase + (lmod >> 1)) : lane;
    const int sB = (lmod < 4) ? (gbase + 3 - (lmod >> 1)) : lane;
    const int idxA = sA << 2, idxB = sB << 2;
    const float signB = (lmod & 1) ? -0.70710678118f : 0.70710678118f;

    const f16x8* fb = (const f16x8*)frags;

    const int nb = (E + 31) >> 5;               // batches of 32 edges
    const int gw = (blockIdx.x << 2) + wv;
    const int nw = gridDim.x << 2;

    for (int b = gw; b < nb; b += nw) {
        const int e0 = b << 5;
        int rn[2], cn[2];
#pragma unroll
        for (int mt = 0; mt < 2; ++mt) {
            int e = e0 + mt * 16 + lmod;
            int ec = (e < E) ? e : (E - 1);
            rn[mt] = ei[ec];
            cn[mt] = ei[E + ec];
        }

        f32x4 tot[2][4];
#pragma unroll
        for (int mt = 0; mt < 2; ++mt)
#pragma unroll
            for (int t = 0; t < 4; ++t) tot[mt][t] = (f32x4){0.f, 0.f, 0.f, 0.f};

#pragma unroll
        for (int l = 0; l < N_LAYERS; ++l) {
            // weight B-frags (L1/L2-hot)
            f16x8 w2f[4][2], mf[4][2];
#pragma unroll
            for (int t = 0; t < 4; ++t)
#pragma unroll
                for (int s = 0; s < 2; ++s) {
                    w2f[t][s] = fb[((l * 2) * 8 + t * 2 + s) * 64 + lane];
                    mf[t][s]  = fb[((l * 2 + 1) * 8 + t * 2 + s) * 64 + lane];
                }
            float b2v[4], gv[4], bev[4];
#pragma unroll
            for (int t = 0; t < 4; ++t) {
                b2v[t] = b2[l * 64 + t * 16 + lmod];
                gv[t]  = gamma[l * 64 + t * 16 + lmod];
                bev[t] = beta[l * 64 + t * 16 + lmod];
            }

            // issue ALL gathers for this layer (8 x 16B, fp16) before compute
            f16x8 g1[2][2], g2[2][2];
#pragma unroll
            for (int mt = 0; mt < 2; ++mt)
#pragma unroll
                for (int s = 0; s < 2; ++s) {
                    g1[mt][s] = *(const f16x8*)(Prow + ((long)rn[mt] * PROW + l * 64 + s * 32 + lgrp * 8));
                    g2[mt][s] = *(const f16x8*)(Pcol + ((long)cn[mt] * PROW + l * 64 + s * 32 + lgrp * 8));
                }

#pragma unroll
            for (int mt = 0; mt < 2; ++mt) {
                // --- A-frag of H = tanh(prow + pcol) (b1 pre-folded)
                f16x8 a[2];
#pragma unroll
                for (int s = 0; s < 2; ++s) {
                    const f16x8 z = g1[mt][s] + g2[mt][s];   // v_pk_add_f16
                    float h[8];
#pragma unroll
                    for (int j = 0; j < 8; ++j) h[j] = tanh_fast((float)z[j]);
                    a[s] = pack_f16(h);
                }

                // --- C1 = H @ W2 + b2
                f32x4 c1[4];
#pragma unroll
                for (int t = 0; t < 4; ++t)
                    c1[t] = (f32x4){b2v[t], b2v[t], b2v[t], b2v[t]};
#pragma unroll
                for (int t = 0; t < 4; ++t)
#pragma unroll
                    for (int s = 0; s < 2; ++s)
                        c1[t] = __builtin_amdgcn_mfma_f32_16x16x32_f16(a[s], w2f[t][s], c1[t], 0, 0, 0);

                // --- LayerNorm rows + write normalized to LDS (pad-68)
#pragma unroll
                for (int r = 0; r < 4; ++r) {
                    float s1 = (c1[0][r] + c1[1][r]) + (c1[2][r] + c1[3][r]);
                    float s2 = __builtin_fmaf(c1[0][r], c1[0][r],
                               __builtin_fmaf(c1[1][r], c1[1][r],
                               __builtin_fmaf(c1[2][r], c1[2][r], c1[3][r] * c1[3][r])));
#pragma unroll
                    for (int off = 1; off < 16; off <<= 1) {
                        s1 += __shfl_xor(s1, off, 64);
                        s2 += __shfl_xor(s2, off, 64);
                    }
                    const float mu = s1 * 0.015625f;
                    const float var = __builtin_fmaf(s2, 0.015625f, -mu * mu);
                    const float rs = __builtin_amdgcn_rsqf(var + 1e-5f);
                    const int rowbase = (lgrp * 4 + r) * 68;
#pragma unroll
                    for (int t = 0; t < 4; ++t) {
                        const float At = rs * gv[t];
                        const float Bt = __builtin_fmaf(-mu, At, bev[t]);
                        mytr[rowbase + lmod + 16 * t] = __builtin_fmaf(c1[t][r], At, Bt);
                    }
                }
                __builtin_amdgcn_wave_barrier();

                // --- transpose-read as A-frag (row=lmod, k=s*32+lgrp*8+j)
                f16x8 a2[2];
#pragma unroll
                for (int s = 0; s < 2; ++s) {
                    const float* rp = mytr + lmod * 68 + s * 32 + lgrp * 8;
                    const float4 q0 = *(const float4*)rp;
                    const float4 q1 = *(const float4*)(rp + 4);
                    const float h[8] = {q0.x, q0.y, q0.z, q0.w, q1.x, q1.y, q1.z, q1.w};
                    a2[s] = pack_f16(h);
                }
                __builtin_amdgcn_wave_barrier();

                // --- C2 = Hn @ M
                f32x4 c2[4];
#pragma unroll
                for (int t = 0; t < 4; ++t) c2[t] = (f32x4){0.f, 0.f, 0.f, 0.f};
#pragma unroll
                for (int t = 0; t < 4; ++t)
#pragma unroll
                    for (int s = 0; s < 2; ++s)
                        c2[t] = __builtin_amdgcn_mfma_f32_16x16x32_f16(a2[s], mf[t][s], c2[t], 0, 0, 0);

                // --- Bell projection on channels 0..3 via ds_bpermute
#pragma unroll
                for (int r = 0; r < 4; ++r) {
                    const float m0 = c2[0][r];
                    const float vA = __int_as_float(__builtin_amdgcn_ds_bpermute(idxA, __float_as_int(m0)));
                    const float vB = __int_as_float(__builtin_amdgcn_ds_bpermute(idxB, __float_as_int(m0)));
                    const float mixed = __builtin_fmaf(vB, signB, vA * 0.70710678118f);
                    tot[mt][0][r] += (lmod < 4) ? mixed : m0;
                }
#pragma unroll
                for (int t = 1; t < 4; ++t) tot[mt][t] += c2[t];
            } // mt
        } // l

        // --- L2 normalize, stage in LDS, coalesced f32x4 stores
#pragma unroll
        for (int mt = 0; mt < 2; ++mt) {
#pragma unroll
            for (int r = 0; r < 4; ++r) {
                float q = __builtin_fmaf(tot[mt][0][r], tot[mt][0][r],
                          __builtin_fmaf(tot[mt][1][r], tot[mt][1][r],
                          __builtin_fmaf(tot[mt][2][r], tot[mt][2][r],
                                         tot[mt][3][r] * tot[mt][3][r])));
#pragma unroll
                for (int off = 1; off < 16; off <<= 1) q += __shfl_xor(q, off, 64);
                const float inv = 1.0f / (sqrtf(q) + 1e-8f);
                const int rowloc = lgrp * 4 + r;
#pragma unroll
                for (int t = 0; t < 4; ++t)
                    mytr[rowloc * 64 + lmod + 16 * t] = tot[mt][t][r] * inv;
            }
            __builtin_amdgcn_wave_barrier();
#pragma unroll
            for (int i = 0; i < 4; ++i) {
                const int row = i * 4 + lgrp;
                const int c4 = lmod * 4;
                const int e = e0 + mt * 16 + row;
                if (e < E) {
                    const f32x4 v = *(const f32x4*)&mytr[row * 64 + c4];
                    *(f32x4*)(out + (long)e * 64 + c4) = v;
                }
            }
            __builtin_amdgcn_wave_barrier();
        }
    }
}

extern "C" void kernel_launch(void* const* d_in, const int* in_sizes, int n_in,
                              void* d_out, int out_size, void* d_ws, size_t ws_size,
                              hipStream_t stream) {
    const float* nf    = (const float*)d_in[0];
    const int*   ei    = (const int*)d_in[1];
    const float* W1    = (const float*)d_in[2];
    const float* b1    = (const float*)d_in[3];
    const float* W2    = (const float*)d_in[4];
    const float* b2    = (const float*)d_in[5];
    const float* gamma = (const float*)d_in[6];
    const float* beta  = (const float*)d_in[7];
    const float* Mw    = (const float*)d_in[8];
    float* out = (float*)d_out;

    const int nNodes = in_sizes[0] / NODE_DIM;
    const int E = in_sizes[1] / 2;

    _Float16* Prow = (_Float16*)d_ws;
    _Float16* Pcol = Prow + (size_t)nNodes * PROW;
    _Float16* frags = Pcol + (size_t)nNodes * PROW;   // 144 frags * 1KB

    build_frags<<<36, 256, 0, stream>>>(W2, Mw, W1, frags);
    proj_mfma<<<(nNodes / 16 + 3) / 4 + 1, 256, 0, stream>>>(nf, frags, b1, Prow, Pcol, nNodes);

    edge_mfma<<<2048, 256, 0, stream>>>(Prow, Pcol, ei, b2, gamma, beta, frags, out, E);
}